// Round 4
// baseline (114.028 us; speedup 1.0000x reference)
//
#include <hip/hip_runtime.h>
#include <math.h>

// Problem constants
#define BSZ   512
#define XD    768
#define YD    128
#define H2D   512

// ---------------------------------------------------------------------------
// ysum: Sy[d]=sum_i y[i,d], Sy2[d]=sum_i y[i,d]^2 (fp64 result), plus zeroing
// of the fp64 accumulators + finalize counter. Grid 32 x 256: block owns 4
// dims, g = t>>2 sums 8 rows.
// ---------------------------------------------------------------------------
__global__ __launch_bounds__(256) void ysum_kernel(
    const float* __restrict__ y, double* __restrict__ Sy,
    double* __restrict__ Sy2, double* __restrict__ accum,
    unsigned int* __restrict__ counter)
{
    const int t  = threadIdx.x;
    const int dl = t & 3;
    const int g  = t >> 2;                     // 0..63, 8 rows each
    const int d  = blockIdx.x * 4 + dl;

    float s = 0.f, s2 = 0.f;
    #pragma unroll
    for (int i = g * 8; i < g * 8 + 8; ++i) {
        const float v = y[i * YD + d];
        s += v; s2 += v * v;
    }
    __shared__ float sh[256];
    __shared__ float sh2[256];
    sh[g * 4 + dl] = s; sh2[g * 4 + dl] = s2;
    __syncthreads();
    if (t < 4) {
        double S = 0.0, S2 = 0.0;
        #pragma unroll
        for (int gg = 0; gg < 64; ++gg) {
            S += (double)sh[gg * 4 + t]; S2 += (double)sh2[gg * 4 + t];
        }
        Sy[blockIdx.x * 4 + t] = S; Sy2[blockIdx.x * 4 + t] = S2;
    } else if (blockIdx.x == 0 && t == 4) { accum[0] = 0.0; }
    else if (blockIdx.x == 0 && t == 5) { accum[1] = 0.0; }
    else if (blockIdx.x == 0 && t == 6) { *counter = 0u; }
}

// ---------------------------------------------------------------------------
// layer1: split-K x4 partials of x @ W1, both branches. NO bias/relu (done in
// layer2 staging). x:(512,768) W1:(768,512) -> p1[br*4+ks][512][512] (8 MB).
// Tile 128x64, 8x4 per thread (48 B LDS -> 32 FMA; a-reads are 4-unique-addr
// per wave = broadcast), K-tile 16, K-chunk 192. Grid (4,8,8) = 256 blocks
// exactly (no tail). Software prefetch of the next K-tile under the FMAs.
// ---------------------------------------------------------------------------
__global__ __launch_bounds__(256) void layer1_kernel(
    const float* __restrict__ x,
    const float* __restrict__ w1_mu, const float* __restrict__ w1_lv,
    float* __restrict__ p1)
{
    __shared__ float As[16][132];   // [k][m], pad->2-way max (free)
    __shared__ float Bs[16][68];    // [k][n]

    const int t      = threadIdx.x;
    const int branch = blockIdx.z >> 2;
    const int ks     = blockIdx.z & 3;
    const float* __restrict__ W = branch ? w1_lv : w1_mu;
    float* __restrict__ out = p1 + (size_t)blockIdx.z * (BSZ * H2D);

    const int m0 = blockIdx.x * 128;
    const int n0 = blockIdx.y * 64;
    const int tx = t & 15;          // 4 cols each
    const int ty = t >> 4;          // 8 rows each

    // staging maps
    const int am  = t >> 1;         // 0..127 (A row)
    const int akq = (t & 1) * 8;    // 0 or 8: two float4 along k
    const int bkk = t >> 4;         // 0..15  (B k-row)
    const int bnq = (t & 15) * 4;   // 0..60  (one float4 along n)

    const int kbase = ks * 192;
    float acc[8][4] = {};

    float4 a_p0 = *(const float4*)&x[(m0 + am) * XD + kbase + akq];
    float4 a_p1 = *(const float4*)&x[(m0 + am) * XD + kbase + akq + 4];
    float4 b_p  = *(const float4*)&W[(kbase + bkk) * H2D + n0 + bnq];

    for (int kt = 0; kt < 192; kt += 16) {
        __syncthreads();            // prev tile's readers done
        As[akq + 0][am] = a_p0.x; As[akq + 1][am] = a_p0.y;
        As[akq + 2][am] = a_p0.z; As[akq + 3][am] = a_p0.w;
        As[akq + 4][am] = a_p1.x; As[akq + 5][am] = a_p1.y;
        As[akq + 6][am] = a_p1.z; As[akq + 7][am] = a_p1.w;
        *(float4*)&Bs[bkk][bnq] = b_p;
        __syncthreads();
        if (kt + 16 < 192) {        // prefetch next tile
            const int kn = kbase + kt + 16;
            a_p0 = *(const float4*)&x[(m0 + am) * XD + kn + akq];
            a_p1 = *(const float4*)&x[(m0 + am) * XD + kn + akq + 4];
            b_p  = *(const float4*)&W[(kn + bkk) * H2D + n0 + bnq];
        }
        #pragma unroll
        for (int k = 0; k < 16; ++k) {
            const float4 a0 = *(const float4*)&As[k][ty * 8];
            const float4 a1 = *(const float4*)&As[k][ty * 8 + 4];
            const float4 bv = *(const float4*)&Bs[k][tx * 4];
            acc[0][0] += a0.x*bv.x; acc[0][1] += a0.x*bv.y; acc[0][2] += a0.x*bv.z; acc[0][3] += a0.x*bv.w;
            acc[1][0] += a0.y*bv.x; acc[1][1] += a0.y*bv.y; acc[1][2] += a0.y*bv.z; acc[1][3] += a0.y*bv.w;
            acc[2][0] += a0.z*bv.x; acc[2][1] += a0.z*bv.y; acc[2][2] += a0.z*bv.z; acc[2][3] += a0.z*bv.w;
            acc[3][0] += a0.w*bv.x; acc[3][1] += a0.w*bv.y; acc[3][2] += a0.w*bv.z; acc[3][3] += a0.w*bv.w;
            acc[4][0] += a1.x*bv.x; acc[4][1] += a1.x*bv.y; acc[4][2] += a1.x*bv.z; acc[4][3] += a1.x*bv.w;
            acc[5][0] += a1.y*bv.x; acc[5][1] += a1.y*bv.y; acc[5][2] += a1.y*bv.z; acc[5][3] += a1.y*bv.w;
            acc[6][0] += a1.z*bv.x; acc[6][1] += a1.z*bv.y; acc[6][2] += a1.z*bv.z; acc[6][3] += a1.z*bv.w;
            acc[7][0] += a1.w*bv.x; acc[7][1] += a1.w*bv.y; acc[7][2] += a1.w*bv.z; acc[7][3] += a1.w*bv.w;
        }
    }

    #pragma unroll
    for (int i = 0; i < 8; ++i) {
        const float4 o = make_float4(acc[i][0], acc[i][1], acc[i][2], acc[i][3]);
        *(float4*)&out[(m0 + ty * 8 + i) * H2D + n0 + tx * 4] = o;
    }
}

// ---------------------------------------------------------------------------
// layer2: split-K x8 partials of relu(sum_ks p1 + b1) @ W2, both branches.
// H recomputed on the fly during A-staging (sum 4 partials + bias + relu).
// H:(512,512) W2:(512,128) -> p2[br*8+ks2][512][128] (4 MB, 16 slices).
// Tile 64x64, 4x4 per thread, K-chunk 64. Grid (8,2,16) = 256 blocks.
// ---------------------------------------------------------------------------
__global__ __launch_bounds__(256) void layer2_kernel(
    const float* __restrict__ p1,
    const float* __restrict__ b1_mu, const float* __restrict__ b1_lv,
    const float* __restrict__ w2_mu, const float* __restrict__ w2_lv,
    float* __restrict__ p2)
{
    __shared__ float As[16][68];
    __shared__ float Bs[16][68];

    const int t      = threadIdx.x;
    const int branch = blockIdx.z >> 3;
    const int ks     = blockIdx.z & 7;
    const float* __restrict__ q0 = p1 + (size_t)(branch * 4 + 0) * (BSZ * H2D);
    const float* __restrict__ q1 = p1 + (size_t)(branch * 4 + 1) * (BSZ * H2D);
    const float* __restrict__ q2 = p1 + (size_t)(branch * 4 + 2) * (BSZ * H2D);
    const float* __restrict__ q3 = p1 + (size_t)(branch * 4 + 3) * (BSZ * H2D);
    const float* __restrict__ b1 = branch ? b1_lv : b1_mu;
    const float* __restrict__ W  = branch ? w2_lv : w2_mu;
    float* __restrict__ out = p2 + (size_t)blockIdx.z * (BSZ * YD);

    const int m0 = blockIdx.x * 64;
    const int n0 = blockIdx.y * 64;
    const int tx = t & 15;
    const int ty = t >> 4;

    const int am  = t >> 2;         // 0..63
    const int akq = (t & 3) * 4;    // one float4 along k
    const int bkk = t >> 4;
    const int bnq = (t & 15) * 4;

    const int kbase = ks * 64;
    float acc[4][4] = {};

    const int arow = (m0 + am) * H2D;
    float4 s0 = *(const float4*)&q0[arow + kbase + akq];
    float4 s1 = *(const float4*)&q1[arow + kbase + akq];
    float4 s2 = *(const float4*)&q2[arow + kbase + akq];
    float4 s3 = *(const float4*)&q3[arow + kbase + akq];
    float4 bb = *(const float4*)&b1[kbase + akq];
    float4 w4 = *(const float4*)&W[(kbase + bkk) * YD + n0 + bnq];

    for (int kt = 0; kt < 64; kt += 16) {
        __syncthreads();
        As[akq + 0][am] = fmaxf(s0.x + s1.x + s2.x + s3.x + bb.x, 0.f);
        As[akq + 1][am] = fmaxf(s0.y + s1.y + s2.y + s3.y + bb.y, 0.f);
        As[akq + 2][am] = fmaxf(s0.z + s1.z + s2.z + s3.z + bb.z, 0.f);
        As[akq + 3][am] = fmaxf(s0.w + s1.w + s2.w + s3.w + bb.w, 0.f);
        *(float4*)&Bs[bkk][bnq] = w4;
        __syncthreads();
        if (kt + 16 < 64) {
            const int kn = kbase + kt + 16;
            s0 = *(const float4*)&q0[arow + kn + akq];
            s1 = *(const float4*)&q1[arow + kn + akq];
            s2 = *(const float4*)&q2[arow + kn + akq];
            s3 = *(const float4*)&q3[arow + kn + akq];
            bb = *(const float4*)&b1[kn + akq];
            w4 = *(const float4*)&W[(kn + bkk) * YD + n0 + bnq];
        }
        #pragma unroll
        for (int k = 0; k < 16; ++k) {
            const float4 av = *(const float4*)&As[k][ty * 4];
            const float4 bv = *(const float4*)&Bs[k][tx * 4];
            acc[0][0] += av.x*bv.x; acc[0][1] += av.x*bv.y; acc[0][2] += av.x*bv.z; acc[0][3] += av.x*bv.w;
            acc[1][0] += av.y*bv.x; acc[1][1] += av.y*bv.y; acc[1][2] += av.y*bv.z; acc[1][3] += av.y*bv.w;
            acc[2][0] += av.z*bv.x; acc[2][1] += av.z*bv.y; acc[2][2] += av.z*bv.z; acc[2][3] += av.z*bv.w;
            acc[3][0] += av.w*bv.x; acc[3][1] += av.w*bv.y; acc[3][2] += av.w*bv.z; acc[3][3] += av.w*bv.w;
        }
    }

    #pragma unroll
    for (int i = 0; i < 4; ++i) {
        const float4 o = make_float4(acc[i][0], acc[i][1], acc[i][2], acc[i][3]);
        *(float4*)&out[(m0 + ty * 4 + i) * YD + n0 + tx * 4] = o;
    }
}

// ---------------------------------------------------------------------------
// reduce (+inline finalize): per element e=(i,d):
//   mu = sum_{s<8} p2[s][e] + b2_mu[d];  lv = tanh(sum_{s>=8} p2[s][e] + b2_lv[d])
//   iv = exp(-lv)
//   pos += -0.5*(mu-y)^2*iv - 0.5*lv
//   ap  += iv*(-0.5*Sy2[d] + mu*Sy[d] - 256*mu^2) - 256*lv
// fp32 elementwise, fp64 block reduction + device atomics; last block (atomic
// counter) finalizes the scalar.
// ---------------------------------------------------------------------------
__global__ __launch_bounds__(256) void reduce_kernel(
    const float* __restrict__ p2, const float* __restrict__ y,
    const float* __restrict__ b2_mu, const float* __restrict__ b2_lv,
    const double* __restrict__ Sy, const double* __restrict__ Sy2,
    double* __restrict__ accum, unsigned int* __restrict__ counter,
    float* __restrict__ outp)
{
    const int NE = BSZ * YD;
    const int e  = blockIdx.x * 256 + threadIdx.x;   // grid 256 covers exactly
    const int d  = e & (YD - 1);

    float mu = b2_mu[d];
    float lp = b2_lv[d];
    #pragma unroll
    for (int s = 0; s < 8; ++s) {
        mu += p2[s * NE + e];
        lp += p2[(8 + s) * NE + e];
    }
    const float lv = tanhf(lp);
    const float iv = expf(-lv);
    const float dm = mu - y[e];

    double pos = -0.5 * (double)dm * (double)dm * (double)iv - 0.5 * (double)lv;
    double ap  = (double)iv * (-0.5 * Sy2[d] + (double)mu * Sy[d]
                               - 256.0 * (double)mu * (double)mu)
               - 256.0 * (double)lv;

    #pragma unroll
    for (int off = 32; off > 0; off >>= 1) {
        pos += __shfl_down(pos, off);
        ap  += __shfl_down(ap, off);
    }
    __shared__ double sp[4];
    __shared__ double sa[4];
    const int lane = threadIdx.x & 63;
    const int wv   = threadIdx.x >> 6;
    if (lane == 0) { sp[wv] = pos; sa[wv] = ap; }
    __syncthreads();
    if (threadIdx.x == 0) {
        atomicAdd(&accum[0], sp[0] + sp[1] + sp[2] + sp[3]);
        atomicAdd(&accum[1], sa[0] + sa[1] + sa[2] + sa[3]);
        __threadfence();
        const unsigned int old = atomicAdd(counter, 1u);
        if (old == 255u) {                 // last block: finalize
            const double P = atomicAdd(&accum[0], 0.0);   // coherent read-back
            const double A = atomicAdd(&accum[1], 0.0);
            const double C = log1p(exp(-20.0) / 511.0);
            outp[0] = (float)(P / 512.0 - A / 262144.0 - C);
        }
    }
}

extern "C" void kernel_launch(void* const* d_in, const int* in_sizes, int n_in,
                              void* d_out, int out_size, void* d_ws, size_t ws_size,
                              hipStream_t stream) {
    const float* x     = (const float*)d_in[0];
    const float* y     = (const float*)d_in[1];
    const float* w1_mu = (const float*)d_in[2];
    const float* b1_mu = (const float*)d_in[3];
    const float* w2_mu = (const float*)d_in[4];
    const float* b2_mu = (const float*)d_in[5];
    const float* w1_lv = (const float*)d_in[6];
    const float* b1_lv = (const float*)d_in[7];
    const float* w2_lv = (const float*)d_in[8];
    const float* b2_lv = (const float*)d_in[9];

    char* ws = (char*)d_ws;
    float*  p1 = (float*)(ws);                                     // 8 MB (8 slices 512x512)
    float*  p2 = (float*)(ws + (size_t)8 * BSZ * H2D * 4);         // 4 MB (16 slices 512x128)
    double* Sy = (double*)(ws + (size_t)8 * BSZ * H2D * 4
                              + (size_t)16 * BSZ * YD * 4);        // 1 KB
    double* Sy2 = Sy + YD;                                         // 1 KB
    double* accum = Sy2 + YD;                                      // 16 B
    unsigned int* counter = (unsigned int*)(accum + 2);            // 4 B

    ysum_kernel<<<32, 256, 0, stream>>>(y, Sy, Sy2, accum, counter);
    layer1_kernel<<<dim3(4, 8, 8), 256, 0, stream>>>(x, w1_mu, w1_lv, p1);
    layer2_kernel<<<dim3(8, 2, 16), 256, 0, stream>>>(
        p1, b1_mu, b1_lv, w2_mu, w2_lv, p2);
    reduce_kernel<<<256, 256, 0, stream>>>(
        p2, y, b2_mu, b2_lv, Sy, Sy2, accum, counter, (float*)d_out);
}

// Round 5
// 112.294 us; speedup vs baseline: 1.0154x; 1.0154x over previous
//
#include <hip/hip_runtime.h>
#include <math.h>

// Problem constants
#define BSZ   512
#define XD    768
#define YD    128
#define H2D   512

// ---------------------------------------------------------------------------
// layer1: split-K x8 partials of x @ W1, both branches. NO bias/relu (applied
// in layer2 staging). x:(512,768) W1:(768,512) -> p1[br*8+ks][512][512] (16MB).
// Tile 128x64, 8x4 per thread, K-tile 16, K-chunk 96. Grid (4,8,16) = 512
// blocks -> 2 blocks/CU (launch_bounds(256,2)) so barrier drains overlap with
// the co-resident block. LDS: As[k][m] stride 132 (scatter 2-way = free),
// Bs[k][n] stride 68. a-reads are 4-unique-address broadcast; b-reads span 64
// consecutive floats (2-way = free).
// ---------------------------------------------------------------------------
__global__ __launch_bounds__(256, 2) void layer1_kernel(
    const float* __restrict__ x,
    const float* __restrict__ w1_mu, const float* __restrict__ w1_lv,
    float* __restrict__ p1)
{
    __shared__ float As[16][132];
    __shared__ float Bs[16][68];

    const int t      = threadIdx.x;
    const int branch = blockIdx.z >> 3;
    const int ks     = blockIdx.z & 7;
    const float* __restrict__ W = branch ? w1_lv : w1_mu;
    float* __restrict__ out = p1 + (size_t)blockIdx.z * (BSZ * H2D);

    const int m0 = blockIdx.x * 128;
    const int n0 = blockIdx.y * 64;
    const int tx = t & 15;          // 4 n-cols at tx*4
    const int ty = t >> 4;          // 8 m-rows at ty*8

    // staging maps: A 128m x 16k (2 float4/thread), B 16k x 64n (1 float4)
    const int am  = t >> 1;         // 0..127
    const int akq = (t & 1) * 8;    // 0 or 8
    const int bkk = t >> 4;         // 0..15
    const int bnq = (t & 15) * 4;   // 0..60

    const int kbase = ks * 96;
    float acc[8][4] = {};

    float4 a0p = *(const float4*)&x[(m0 + am) * XD + kbase + akq];
    float4 a1p = *(const float4*)&x[(m0 + am) * XD + kbase + akq + 4];
    float4 bp  = *(const float4*)&W[(kbase + bkk) * H2D + n0 + bnq];

    for (int kt = 0; kt < 96; kt += 16) {
        __syncthreads();            // prev tile's readers done
        As[akq + 0][am] = a0p.x; As[akq + 1][am] = a0p.y;
        As[akq + 2][am] = a0p.z; As[akq + 3][am] = a0p.w;
        As[akq + 4][am] = a1p.x; As[akq + 5][am] = a1p.y;
        As[akq + 6][am] = a1p.z; As[akq + 7][am] = a1p.w;
        *(float4*)&Bs[bkk][bnq] = bp;
        __syncthreads();
        if (kt + 16 < 96) {         // prefetch next tile under the FMAs
            const int kn = kbase + kt + 16;
            a0p = *(const float4*)&x[(m0 + am) * XD + kn + akq];
            a1p = *(const float4*)&x[(m0 + am) * XD + kn + akq + 4];
            bp  = *(const float4*)&W[(kn + bkk) * H2D + n0 + bnq];
        }
        #pragma unroll
        for (int k = 0; k < 16; ++k) {
            const float4 a0 = *(const float4*)&As[k][ty * 8];
            const float4 a1 = *(const float4*)&As[k][ty * 8 + 4];
            const float4 bv = *(const float4*)&Bs[k][tx * 4];
            acc[0][0] += a0.x*bv.x; acc[0][1] += a0.x*bv.y; acc[0][2] += a0.x*bv.z; acc[0][3] += a0.x*bv.w;
            acc[1][0] += a0.y*bv.x; acc[1][1] += a0.y*bv.y; acc[1][2] += a0.y*bv.z; acc[1][3] += a0.y*bv.w;
            acc[2][0] += a0.z*bv.x; acc[2][1] += a0.z*bv.y; acc[2][2] += a0.z*bv.z; acc[2][3] += a0.z*bv.w;
            acc[3][0] += a0.w*bv.x; acc[3][1] += a0.w*bv.y; acc[3][2] += a0.w*bv.z; acc[3][3] += a0.w*bv.w;
            acc[4][0] += a1.x*bv.x; acc[4][1] += a1.x*bv.y; acc[4][2] += a1.x*bv.z; acc[4][3] += a1.x*bv.w;
            acc[5][0] += a1.y*bv.x; acc[5][1] += a1.y*bv.y; acc[5][2] += a1.y*bv.z; acc[5][3] += a1.y*bv.w;
            acc[6][0] += a1.z*bv.x; acc[6][1] += a1.z*bv.y; acc[6][2] += a1.z*bv.z; acc[6][3] += a1.z*bv.w;
            acc[7][0] += a1.w*bv.x; acc[7][1] += a1.w*bv.y; acc[7][2] += a1.w*bv.z; acc[7][3] += a1.w*bv.w;
        }
    }

    #pragma unroll
    for (int i = 0; i < 8; ++i) {
        const float4 o = make_float4(acc[i][0], acc[i][1], acc[i][2], acc[i][3]);
        *(float4*)&out[(m0 + ty * 8 + i) * H2D + n0 + tx * 4] = o;
    }
}

// ---------------------------------------------------------------------------
// layer2 (+ ysum plane): split-K x16 partials of relu(sum_8 p1 + b1) @ W2.
// H:(512,512) W2:(512,128) -> p2[br*16+ks2][512][128] (8 MB, 32 slices).
// Tile 32x128 (full N, so each p1 element is read exactly once), 2x(2x4) per
// thread with the N dimension split into two 64-col halves so every LDS b128
// read spans <=64 consecutive floats (2-way = free). K-chunk 32 (2 k-tiles).
// Grid (16,1,33) = 528: z<32 GEMM (branch=z>>4, ks2=z&15); z==32 = ysum:
// 16 blocks compute Sy/Sy2 (fp64) and zero the accumulators + counter.
// ---------------------------------------------------------------------------
__global__ __launch_bounds__(256, 2) void layer2_kernel(
    const float* __restrict__ p1,
    const float* __restrict__ b1_mu, const float* __restrict__ b1_lv,
    const float* __restrict__ w2_mu, const float* __restrict__ w2_lv,
    const float* __restrict__ y,
    float* __restrict__ p2,
    double* __restrict__ Sy, double* __restrict__ Sy2,
    double* __restrict__ accum, unsigned int* __restrict__ counter)
{
    __shared__ float As[16][36];    // [k][m] 32+4 pad
    __shared__ float Bs[16][132];   // [k][n] 128+4 pad
    const int t = threadIdx.x;

    if (blockIdx.z == 32) {
        // ----- ysum plane -----
        const int id = blockIdx.x;           // 0..15, 8 dims each
        const int dl = t & 7;
        const int g  = t >> 3;               // 0..31, 16 rows each
        const int d  = id * 8 + dl;
        float s = 0.f, s2 = 0.f;
        #pragma unroll
        for (int i = g * 16; i < g * 16 + 16; ++i) {
            const float v = y[i * YD + d];
            s += v; s2 += v * v;
        }
        float* shs  = &As[0][0];             // reuse LDS (256 floats needed)
        float* shs2 = &Bs[0][0];
        shs[t] = s; shs2[t] = s2;
        __syncthreads();
        if (t < 8) {
            double S = 0.0, S2 = 0.0;
            #pragma unroll
            for (int gg = 0; gg < 32; ++gg) {
                S += (double)shs[gg * 8 + t]; S2 += (double)shs2[gg * 8 + t];
            }
            Sy[id * 8 + t] = S; Sy2[id * 8 + t] = S2;
        } else if (id == 0 && t == 8)  { accum[0] = 0.0; }
        else if (id == 0 && t == 9)  { accum[1] = 0.0; }
        else if (id == 0 && t == 10) { *counter = 0u; }
        return;
    }

    // ----- GEMM planes -----
    const int branch = blockIdx.z >> 4;
    const int ks2    = blockIdx.z & 15;
    const float* __restrict__ q  = p1 + (size_t)(branch * 8) * (BSZ * H2D);
    const float* __restrict__ b1 = branch ? b1_lv : b1_mu;
    const float* __restrict__ W  = branch ? w2_lv : w2_mu;
    float* __restrict__ out = p2 + (size_t)blockIdx.z * (BSZ * YD);

    const int m0 = blockIdx.x * 32;
    const int tx = t & 15;          // n: two half-cols at tx*4 and 64+tx*4
    const int ty = t >> 4;          // m: 2 rows at ty*2

    // staging maps: A 32m x 16k by t<128 (1 float4, summing 8 p1 slices +
    // bias + relu); B 16k x 128n by all threads (2 float4).
    const int am  = t >> 2;         // 0..63 -> rows 0..31 when t<128
    const int akq = (t & 3) * 4;
    const int bkk = t >> 4;         // 0..15
    const int bnq = (t & 15) * 8;   // 0..120

    const int kbase = ks2 * 32;
    float acc[2][2][4] = {};        // [m-row][n-half][n-col]

    // prefetch tile 0
    float4 aval, bb4;
    if (t < 128) {
        const int arow = (m0 + am) * H2D + kbase + akq;
        aval = *(const float4*)&q[arow];
        #pragma unroll
        for (int s = 1; s < 8; ++s) {
            const float4 v = *(const float4*)&q[(size_t)s * (BSZ * H2D) + arow];
            aval.x += v.x; aval.y += v.y; aval.z += v.z; aval.w += v.w;
        }
        bb4 = *(const float4*)&b1[kbase + akq];
    }
    float4 w0 = *(const float4*)&W[(kbase + bkk) * YD + bnq];
    float4 w1 = *(const float4*)&W[(kbase + bkk) * YD + bnq + 4];

    for (int kt = 0; kt < 32; kt += 16) {
        __syncthreads();
        if (t < 128) {
            As[akq + 0][am] = fmaxf(aval.x + bb4.x, 0.f);
            As[akq + 1][am] = fmaxf(aval.y + bb4.y, 0.f);
            As[akq + 2][am] = fmaxf(aval.z + bb4.z, 0.f);
            As[akq + 3][am] = fmaxf(aval.w + bb4.w, 0.f);
        }
        *(float4*)&Bs[bkk][bnq]     = w0;
        *(float4*)&Bs[bkk][bnq + 4] = w1;
        __syncthreads();
        if (kt == 0) {              // prefetch tile 1
            const int kn = kbase + 16;
            if (t < 128) {
                const int arow = (m0 + am) * H2D + kn + akq;
                aval = *(const float4*)&q[arow];
                #pragma unroll
                for (int s = 1; s < 8; ++s) {
                    const float4 v = *(const float4*)&q[(size_t)s * (BSZ * H2D) + arow];
                    aval.x += v.x; aval.y += v.y; aval.z += v.z; aval.w += v.w;
                }
                bb4 = *(const float4*)&b1[kn + akq];
            }
            w0 = *(const float4*)&W[(kn + bkk) * YD + bnq];
            w1 = *(const float4*)&W[(kn + bkk) * YD + bnq + 4];
        }
        #pragma unroll
        for (int k = 0; k < 16; ++k) {
            const float a0 = As[k][ty * 2 + 0];
            const float a1 = As[k][ty * 2 + 1];
            const float4 v0 = *(const float4*)&Bs[k][tx * 4];
            const float4 v1 = *(const float4*)&Bs[k][64 + tx * 4];
            acc[0][0][0] += a0*v0.x; acc[0][0][1] += a0*v0.y; acc[0][0][2] += a0*v0.z; acc[0][0][3] += a0*v0.w;
            acc[0][1][0] += a0*v1.x; acc[0][1][1] += a0*v1.y; acc[0][1][2] += a0*v1.z; acc[0][1][3] += a0*v1.w;
            acc[1][0][0] += a1*v0.x; acc[1][0][1] += a1*v0.y; acc[1][0][2] += a1*v0.z; acc[1][0][3] += a1*v0.w;
            acc[1][1][0] += a1*v1.x; acc[1][1][1] += a1*v1.y; acc[1][1][2] += a1*v1.z; acc[1][1][3] += a1*v1.w;
        }
    }

    #pragma unroll
    for (int r = 0; r < 2; ++r) {
        const int row = (m0 + ty * 2 + r) * YD;
        float4 o0 = make_float4(acc[r][0][0], acc[r][0][1], acc[r][0][2], acc[r][0][3]);
        float4 o1 = make_float4(acc[r][1][0], acc[r][1][1], acc[r][1][2], acc[r][1][3]);
        *(float4*)&out[row + tx * 4]      = o0;
        *(float4*)&out[row + 64 + tx * 4] = o1;
    }
}

// ---------------------------------------------------------------------------
// reduce (+inline finalize): per element e=(i,d):
//   mu = sum_{s<16} p2[s][e] + b2_mu[d]; lv = tanh(sum_{s>=16} p2[s][e] + b2_lv[d])
//   iv = exp(-lv)
//   pos += -0.5*(mu-y)^2*iv - 0.5*lv
//   ap  += iv*(-0.5*Sy2[d] + mu*Sy[d] - 256*mu^2) - 256*lv
// fp32 elementwise, fp64 block reduction + device atomics; last block (atomic
// counter) finalizes: out = pos/B - ap/B^2 - log1p(exp(-20)/(B-1)).
// ---------------------------------------------------------------------------
__global__ __launch_bounds__(256) void reduce_kernel(
    const float* __restrict__ p2, const float* __restrict__ y,
    const float* __restrict__ b2_mu, const float* __restrict__ b2_lv,
    const double* __restrict__ Sy, const double* __restrict__ Sy2,
    double* __restrict__ accum, unsigned int* __restrict__ counter,
    float* __restrict__ outp)
{
    const int NE = BSZ * YD;
    const int e  = blockIdx.x * 256 + threadIdx.x;   // grid 256 covers exactly
    const int d  = e & (YD - 1);

    float mu = b2_mu[d];
    float lp = b2_lv[d];
    #pragma unroll
    for (int s = 0; s < 16; ++s) {
        mu += p2[s * NE + e];
        lp += p2[(16 + s) * NE + e];
    }
    const float lv = tanhf(lp);
    const float iv = expf(-lv);
    const float dm = mu - y[e];

    double pos = -0.5 * (double)dm * (double)dm * (double)iv - 0.5 * (double)lv;
    double ap  = (double)iv * (-0.5 * Sy2[d] + (double)mu * Sy[d]
                               - 256.0 * (double)mu * (double)mu)
               - 256.0 * (double)lv;

    #pragma unroll
    for (int off = 32; off > 0; off >>= 1) {
        pos += __shfl_down(pos, off);
        ap  += __shfl_down(ap, off);
    }
    __shared__ double sp[4];
    __shared__ double sa[4];
    const int lane = threadIdx.x & 63;
    const int wv   = threadIdx.x >> 6;
    if (lane == 0) { sp[wv] = pos; sa[wv] = ap; }
    __syncthreads();
    if (threadIdx.x == 0) {
        atomicAdd(&accum[0], sp[0] + sp[1] + sp[2] + sp[3]);
        atomicAdd(&accum[1], sa[0] + sa[1] + sa[2] + sa[3]);
        __threadfence();
        const unsigned int old = atomicAdd(counter, 1u);
        if (old == 255u) {                 // last block: finalize
            const double P = atomicAdd(&accum[0], 0.0);   // coherent read-back
            const double A = atomicAdd(&accum[1], 0.0);
            const double C = log1p(exp(-20.0) / 511.0);
            outp[0] = (float)(P / 512.0 - A / 262144.0 - C);
        }
    }
}

extern "C" void kernel_launch(void* const* d_in, const int* in_sizes, int n_in,
                              void* d_out, int out_size, void* d_ws, size_t ws_size,
                              hipStream_t stream) {
    const float* x     = (const float*)d_in[0];
    const float* y     = (const float*)d_in[1];
    const float* w1_mu = (const float*)d_in[2];
    const float* b1_mu = (const float*)d_in[3];
    const float* w2_mu = (const float*)d_in[4];
    const float* b2_mu = (const float*)d_in[5];
    const float* w1_lv = (const float*)d_in[6];
    const float* b1_lv = (const float*)d_in[7];
    const float* w2_lv = (const float*)d_in[8];
    const float* b2_lv = (const float*)d_in[9];

    char* ws = (char*)d_ws;
    float*  p1 = (float*)(ws);                                     // 16 MB (16 slices 512x512)
    float*  p2 = (float*)(ws + (size_t)16 * BSZ * H2D * 4);        // 8 MB (32 slices 512x128)
    double* Sy = (double*)(ws + (size_t)16 * BSZ * H2D * 4
                              + (size_t)32 * BSZ * YD * 4);        // 1 KB
    double* Sy2 = Sy + YD;                                         // 1 KB
    double* accum = Sy2 + YD;                                      // 16 B
    unsigned int* counter = (unsigned int*)(accum + 2);            // 4 B

    layer1_kernel<<<dim3(4, 8, 16), 256, 0, stream>>>(x, w1_mu, w1_lv, p1);
    layer2_kernel<<<dim3(16, 1, 33), 256, 0, stream>>>(
        p1, b1_mu, b1_lv, w2_mu, w2_lv, y, p2, Sy, Sy2, accum, counter);
    reduce_kernel<<<256, 256, 0, stream>>>(
        p2, y, b2_mu, b2_lv, Sy, Sy2, accum, counter, (float*)d_out);
}